// Round 5
// baseline (46.174 us; speedup 1.0000x reference)
//
#include <hip/hip_runtime.h>
#include <hip/hip_fp16.h>

// Bilateral slice: grid (4,12,8,16,16) f32, guide (4,1,1024,1024) f32
// out (4,12,1024,1024) f32.
// Block = one output row (b,y). y-lerp folded into a 6KB packed-f16 LDS tile:
// smem[z][q][slot] (uint4) = 4 f16 channels of quad q at x AND x+1, with
// slot=(x+5z)&15 so the random per-lane z spreads the b128 start bank over
// all 8 phases (z,q strides are multiples of 32 banks -> invisible).
// Per pixel: 6 ds_read_b128 + packed v_pk_fma_f16 x/z lerps.
// Thread = 4 consecutive x pixels; batched acc, 12 coalesced f4 stores.
// Round 5 (single-variable A/B vs round 4): NON-TEMPORAL output stores —
// out is written once and never read; bypass L2 retention.

typedef float f4 __attribute__((ext_vector_type(4)));
typedef unsigned int u32;

__global__ __launch_bounds__(256) void bilateral_slice_kernel(
    const float* __restrict__ grid,
    const float* __restrict__ guide,
    float* __restrict__ out)
{
    constexpr float S = 15.0f / 1023.0f;   // linspace step (0..15 over 1024)

    __shared__ uint4 smem[8 * 3 * 16];     // [z][q][slot], 6 KB

    int blk = blockIdx.x;                  // 0..4095
    int b   = blk >> 10;                   // batch
    int y   = blk & 1023;                  // output row

    // Guide load first so its HBM latency overlaps the staging phase.
    int xp = threadIdx.x << 2;
    const f4 gv = *reinterpret_cast<const f4*>(
        guide + ((size_t)b << 20) + ((size_t)y << 10) + xp);

    // Row-uniform y interpolation. min(floor,14)+f == reference clip
    // (f->1.0 at the top edge returns the endpoint).
    float iy = y * S;
    int   y0 = min((int)iy, 14);
    float fy = iy - (float)y0;

    // Stage y-interpolated row as packed f16 with x-pair duplication.
    const float* gb = grid + (size_t)b * (12 * 2048) + y0 * 16;
    for (int i = threadIdx.x; i < 384; i += 256) {
        int x  = i & 15;
        int w  = i >> 4;                   // 0..23
        int q  = w % 3;
        int z  = w / 3;
        int x1 = min(x + 1, 15);           // x=15 slot is never read; avoid OOB
        const float* p = gb + z * 256 + q * (4 * 2048);
        float r0[4], r1[4];
        #pragma unroll
        for (int k = 0; k < 4; ++k) {
            const float* pc = p + k * 2048;
            float a0 = pc[x],  a1 = pc[x + 16];    // (x,  y0) (x,  y0+1)
            float b0 = pc[x1], b1 = pc[x1 + 16];   // (x1, y0) (x1, y0+1)
            r0[k] = fmaf(fy, a1 - a0, a0);
            r1[k] = fmaf(fy, b1 - b0, b0);
        }
        uint4 u;
        __half2 h;
        h = __floats2half2_rn(r0[0], r0[1]); u.x = *(u32*)&h;
        h = __floats2half2_rn(r0[2], r0[3]); u.y = *(u32*)&h;
        h = __floats2half2_rn(r1[0], r1[1]); u.z = *(u32*)&h;
        h = __floats2half2_rn(r1[2], r1[3]); u.w = *(u32*)&h;
        smem[z * 48 + q * 16 + ((x + 5 * z) & 15)] = u;
    }
    __syncthreads();

    __half2 acc01[3][4], acc23[3][4];      // [quad][px], (c0,c1)/(c2,c3) packed

    #pragma unroll
    for (int j = 0; j < 4; ++j) {
        float ix  = (float)(xp + j) * S;
        int   x0  = min((int)ix, 14);
        float fxf = ix - (float)x0;
        float gz  = fminf(fmaxf(gv[j], 0.0f), 1.0f) * 7.0f;
        int   z0  = min((int)gz, 6);
        float fzf = gz - (float)z0;
        __half2 fx2 = __float2half2_rn(fxf);
        __half2 fz2 = __float2half2_rn(fzf);
        int i0 = z0 * 48 + ((x0 + 5 * z0) & 15);
        int i1 = i0 + 48 + (((x0 + 5 * (z0 + 1)) & 15) - ((x0 + 5 * z0) & 15));

        #pragma unroll
        for (int q = 0; q < 3; ++q) {
            uint4 A = smem[i0 + q * 16];   // (z0): c0..c3 @ x0, x0+1
            uint4 B = smem[i1 + q * 16];   // (z0+1)
            __half2 a01 = *(__half2*)&A.x, a23 = *(__half2*)&A.y;
            __half2 b01 = *(__half2*)&A.z, b23 = *(__half2*)&A.w;
            __half2 c01 = *(__half2*)&B.x, c23 = *(__half2*)&B.y;
            __half2 d01 = *(__half2*)&B.z, d23 = *(__half2*)&B.w;
            __half2 e01 = __hfma2(fx2, __hsub2(b01, a01), a01);
            __half2 e23 = __hfma2(fx2, __hsub2(b23, a23), a23);
            __half2 f01 = __hfma2(fx2, __hsub2(d01, c01), c01);
            __half2 f23 = __hfma2(fx2, __hsub2(d23, c23), c23);
            acc01[q][j] = __hfma2(fz2, __hsub2(f01, e01), e01);
            acc23[q][j] = __hfma2(fz2, __hsub2(f23, e23), e23);
        }
    }

    size_t obase = ((size_t)(b * 12) << 20) + (size_t)((y << 10) + xp);
    #pragma unroll
    for (int q = 0; q < 3; ++q) {
        f4 v;
        v = (f4){__low2float(acc01[q][0]),  __low2float(acc01[q][1]),
                 __low2float(acc01[q][2]),  __low2float(acc01[q][3])};
        __builtin_nontemporal_store(v, reinterpret_cast<f4*>(
            out + obase + ((size_t)(4*q+0) << 20)));
        v = (f4){__high2float(acc01[q][0]), __high2float(acc01[q][1]),
                 __high2float(acc01[q][2]), __high2float(acc01[q][3])};
        __builtin_nontemporal_store(v, reinterpret_cast<f4*>(
            out + obase + ((size_t)(4*q+1) << 20)));
        v = (f4){__low2float(acc23[q][0]),  __low2float(acc23[q][1]),
                 __low2float(acc23[q][2]),  __low2float(acc23[q][3])};
        __builtin_nontemporal_store(v, reinterpret_cast<f4*>(
            out + obase + ((size_t)(4*q+2) << 20)));
        v = (f4){__high2float(acc23[q][0]), __high2float(acc23[q][1]),
                 __high2float(acc23[q][2]), __high2float(acc23[q][3])};
        __builtin_nontemporal_store(v, reinterpret_cast<f4*>(
            out + obase + ((size_t)(4*q+3) << 20)));
    }
}

extern "C" void kernel_launch(void* const* d_in, const int* in_sizes, int n_in,
                              void* d_out, int out_size, void* d_ws, size_t ws_size,
                              hipStream_t stream) {
    const float* grid  = (const float*)d_in[0];
    const float* guide = (const float*)d_in[1];
    float* out = (float*)d_out;

    // 4 batches * 1024 rows = 4096 blocks; 256 threads = 4 px/thread.
    dim3 grd(4096), blk(256);
    hipLaunchKernelGGL(bilateral_slice_kernel, grd, blk, 0, stream,
                       grid, guide, out);
}

// Round 6
// 40.790 us; speedup vs baseline: 1.1320x; 1.1320x over previous
//
#include <hip/hip_runtime.h>
#include <hip/hip_fp16.h>

// Bilateral slice: grid (4,12,8,16,16) f32, guide (4,1,1024,1024) f32
// out (4,12,1024,1024) f32.
// Block = TWO output rows (b, 2k / 2k+1): per-row y-lerp folded into a 6KB
// packed-f16 LDS tile each (12KB total): smem[r][z][q][slot] (uint4) = 4 f16
// channels of quad q at x AND x+1, slot=(x+5z)&15 spreads the random per-lane
// z over all 8 b128 start-bank phases (z,q strides are bank-invisible).
// Per pixel: 6 ds_read_b128 + packed v_pk_fma_f16 x/z lerps.
// Thread = 4 consecutive x pixels per row; rows processed sequentially so
// live acc stays 12 half2. Plain (cached) stores — NT stores measured -15%.

typedef float f4 __attribute__((ext_vector_type(4)));
typedef unsigned int u32;

__global__ __launch_bounds__(256) void bilateral_slice_kernel(
    const float* __restrict__ grid,
    const float* __restrict__ guide,
    float* __restrict__ out)
{
    constexpr float S = 15.0f / 1023.0f;   // linspace step (0..15 over 1024)

    __shared__ uint4 smem[2 * 8 * 3 * 16]; // [row][z][q][slot], 12 KB

    int blk = blockIdx.x;                  // 0..2047
    int b   = blk >> 9;                    // batch
    int k   = blk & 511;
    int r0  = k << 1;                      // rows r0, r0+1

    // Guide loads first so their HBM latency overlaps the staging phase.
    int xp = threadIdx.x << 2;
    const float* gp = guide + ((size_t)b << 20) + ((size_t)r0 << 10) + xp;
    const f4 gv0 = *reinterpret_cast<const f4*>(gp);
    const f4 gv1 = *reinterpret_cast<const f4*>(gp + 1024);

    // Per-row y interpolation. min(floor,14)+f == reference clip
    // (f->1.0 at the top edge returns the endpoint).
    int   y0[2];
    float fy[2];
    #pragma unroll
    for (int r = 0; r < 2; ++r) {
        float iy = (r0 + r) * S;
        y0[r] = min((int)iy, 14);
        fy[r] = iy - (float)y0[r];
    }

    // Stage both rows' y-interpolated tiles as packed f16 with x-pair dup.
    // 768 items over 256 threads = exactly 3 iterations each.
    const float* gbase = grid + (size_t)b * (12 * 2048);
    for (int i = threadIdx.x; i < 768; i += 256) {
        int r  = i >= 384;
        int ii = i - (r ? 384 : 0);
        int x  = ii & 15;
        int w  = ii >> 4;                  // 0..23
        int q  = w % 3;
        int z  = w / 3;
        int x1 = min(x + 1, 15);           // x=15 slot never read; avoid OOB
        float fyr = fy[r];
        const float* p = gbase + y0[r] * 16 + z * 256 + q * (4 * 2048);
        float v0[4], v1[4];
        #pragma unroll
        for (int c = 0; c < 4; ++c) {
            const float* pc = p + c * 2048;
            float a0 = pc[x],  a1 = pc[x + 16];
            float b0 = pc[x1], b1 = pc[x1 + 16];
            v0[c] = fmaf(fyr, a1 - a0, a0);
            v1[c] = fmaf(fyr, b1 - b0, b0);
        }
        uint4 u;
        __half2 h;
        h = __floats2half2_rn(v0[0], v0[1]); u.x = *(u32*)&h;
        h = __floats2half2_rn(v0[2], v0[3]); u.y = *(u32*)&h;
        h = __floats2half2_rn(v1[0], v1[1]); u.z = *(u32*)&h;
        h = __floats2half2_rn(v1[2], v1[3]); u.w = *(u32*)&h;
        smem[r * 384 + z * 48 + q * 16 + ((x + 5 * z) & 15)] = u;
    }
    __syncthreads();

    // fx/x0 depend only on x: shared by both rows.
    float fxv[4];
    int   x0v[4];
    #pragma unroll
    for (int j = 0; j < 4; ++j) {
        float ix = (float)(xp + j) * S;
        x0v[j] = min((int)ix, 14);
        fxv[j] = ix - (float)x0v[j];
    }

    size_t obase = ((size_t)(b * 12) << 20) + (size_t)((r0 << 10) + xp);

    #pragma unroll
    for (int r = 0; r < 2; ++r) {
        const f4 gv = r ? gv1 : gv0;
        const uint4* sm = smem + r * 384;
        __half2 acc01[3][4], acc23[3][4];  // [quad][px]

        #pragma unroll
        for (int j = 0; j < 4; ++j) {
            int   x0  = x0v[j];
            float gz  = fminf(fmaxf(gv[j], 0.0f), 1.0f) * 7.0f;
            int   z0  = min((int)gz, 6);
            float fzf = gz - (float)z0;
            __half2 fx2 = __float2half2_rn(fxv[j]);
            __half2 fz2 = __float2half2_rn(fzf);
            int i0 = z0 * 48 + ((x0 + 5 * z0) & 15);
            int i1 = i0 + 48 + (((x0 + 5 * (z0 + 1)) & 15) - ((x0 + 5 * z0) & 15));

            #pragma unroll
            for (int q = 0; q < 3; ++q) {
                uint4 A = sm[i0 + q * 16];   // (z0): c0..c3 @ x0, x0+1
                uint4 B = sm[i1 + q * 16];   // (z0+1)
                __half2 a01 = *(__half2*)&A.x, a23 = *(__half2*)&A.y;
                __half2 b01 = *(__half2*)&A.z, b23 = *(__half2*)&A.w;
                __half2 c01 = *(__half2*)&B.x, c23 = *(__half2*)&B.y;
                __half2 d01 = *(__half2*)&B.z, d23 = *(__half2*)&B.w;
                __half2 e01 = __hfma2(fx2, __hsub2(b01, a01), a01);
                __half2 e23 = __hfma2(fx2, __hsub2(b23, a23), a23);
                __half2 f01 = __hfma2(fx2, __hsub2(d01, c01), c01);
                __half2 f23 = __hfma2(fx2, __hsub2(d23, c23), c23);
                acc01[q][j] = __hfma2(fz2, __hsub2(f01, e01), e01);
                acc23[q][j] = __hfma2(fz2, __hsub2(f23, e23), e23);
            }
        }

        size_t ob = obase + (size_t)(r << 10);
        #pragma unroll
        for (int q = 0; q < 3; ++q) {
            f4 v;
            v = (f4){__low2float(acc01[q][0]),  __low2float(acc01[q][1]),
                     __low2float(acc01[q][2]),  __low2float(acc01[q][3])};
            *reinterpret_cast<f4*>(out + ob + ((size_t)(4*q+0) << 20)) = v;
            v = (f4){__high2float(acc01[q][0]), __high2float(acc01[q][1]),
                     __high2float(acc01[q][2]), __high2float(acc01[q][3])};
            *reinterpret_cast<f4*>(out + ob + ((size_t)(4*q+1) << 20)) = v;
            v = (f4){__low2float(acc23[q][0]),  __low2float(acc23[q][1]),
                     __low2float(acc23[q][2]),  __low2float(acc23[q][3])};
            *reinterpret_cast<f4*>(out + ob + ((size_t)(4*q+2) << 20)) = v;
            v = (f4){__high2float(acc23[q][0]), __high2float(acc23[q][1]),
                     __high2float(acc23[q][2]), __high2float(acc23[q][3])};
            *reinterpret_cast<f4*>(out + ob + ((size_t)(4*q+3) << 20)) = v;
        }
    }
}

extern "C" void kernel_launch(void* const* d_in, const int* in_sizes, int n_in,
                              void* d_out, int out_size, void* d_ws, size_t ws_size,
                              hipStream_t stream) {
    const float* grid  = (const float*)d_in[0];
    const float* guide = (const float*)d_in[1];
    float* out = (float*)d_out;

    // 4 batches * 512 row-pairs = 2048 blocks; 256 threads = 4 px/thread/row.
    dim3 grd(2048), blk(256);
    hipLaunchKernelGGL(bilateral_slice_kernel, grd, blk, 0, stream,
                       grid, guide, out);
}

// Round 7
// 39.270 us; speedup vs baseline: 1.1758x; 1.0387x over previous
//
#include <hip/hip_runtime.h>
#include <hip/hip_fp16.h>

// Bilateral slice: grid (4,12,8,16,16) f32, guide (4,1,1024,1024) f32
// out (4,12,1024,1024) f32.
// Block = one output row (b,y). y-lerp folded into a 6KB packed-f16 LDS tile:
// smem[z][q][slot] (uint4) = 4 f16 channels of quad q at x AND x+1, with
// slot=(x+5z)&15 so the random per-lane z spreads the b128 start bank over
// all 8 phases (z,q strides are multiples of 32 banks -> invisible).
// Per pixel: 6 ds_read_b128 + packed v_pk_fma_f16 x/z lerps.
// Round 7 (single-variable A/B vs round 4): channel-quads processed
// SEQUENTIALLY with immediate plain stores — spreads the 12-store burst
// across the wave lifetime and shrinks live acc 24->8 half2.
// (NT stores: measured -15%. R=2 rows/block: measured neutral.)

typedef float f4 __attribute__((ext_vector_type(4)));
typedef unsigned int u32;

__global__ __launch_bounds__(256) void bilateral_slice_kernel(
    const float* __restrict__ grid,
    const float* __restrict__ guide,
    float* __restrict__ out)
{
    constexpr float S = 15.0f / 1023.0f;   // linspace step (0..15 over 1024)

    __shared__ uint4 smem[8 * 3 * 16];     // [z][q][slot], 6 KB

    int blk = blockIdx.x;                  // 0..4095
    int b   = blk >> 10;                   // batch
    int y   = blk & 1023;                  // output row

    // Guide load first so its HBM latency overlaps the staging phase.
    int xp = threadIdx.x << 2;
    const f4 gv = *reinterpret_cast<const f4*>(
        guide + ((size_t)b << 20) + ((size_t)y << 10) + xp);

    // Row-uniform y interpolation. min(floor,14)+f == reference clip
    // (f->1.0 at the top edge returns the endpoint).
    float iy = y * S;
    int   y0 = min((int)iy, 14);
    float fy = iy - (float)y0;

    // Stage y-interpolated row as packed f16 with x-pair duplication.
    const float* gb = grid + (size_t)b * (12 * 2048) + y0 * 16;
    for (int i = threadIdx.x; i < 384; i += 256) {
        int x  = i & 15;
        int w  = i >> 4;                   // 0..23
        int q  = w % 3;
        int z  = w / 3;
        int x1 = min(x + 1, 15);           // x=15 slot is never read; avoid OOB
        const float* p = gb + z * 256 + q * (4 * 2048);
        float r0[4], r1[4];
        #pragma unroll
        for (int k = 0; k < 4; ++k) {
            const float* pc = p + k * 2048;
            float a0 = pc[x],  a1 = pc[x + 16];    // (x,  y0) (x,  y0+1)
            float b0 = pc[x1], b1 = pc[x1 + 16];   // (x1, y0) (x1, y0+1)
            r0[k] = fmaf(fy, a1 - a0, a0);
            r1[k] = fmaf(fy, b1 - b0, b0);
        }
        uint4 u;
        __half2 h;
        h = __floats2half2_rn(r0[0], r0[1]); u.x = *(u32*)&h;
        h = __floats2half2_rn(r0[2], r0[3]); u.y = *(u32*)&h;
        h = __floats2half2_rn(r1[0], r1[1]); u.z = *(u32*)&h;
        h = __floats2half2_rn(r1[2], r1[3]); u.w = *(u32*)&h;
        smem[z * 48 + q * 16 + ((x + 5 * z) & 15)] = u;
    }
    __syncthreads();

    // Per-pixel params, hoisted out of the quad loop.
    __half2 fx2[4], fz2[4];
    int i0[4], i1[4];
    #pragma unroll
    for (int j = 0; j < 4; ++j) {
        float ix  = (float)(xp + j) * S;
        int   x0  = min((int)ix, 14);
        fx2[j] = __float2half2_rn(ix - (float)x0);
        float gz  = fminf(fmaxf(gv[j], 0.0f), 1.0f) * 7.0f;
        int   z0  = min((int)gz, 6);
        fz2[j] = __float2half2_rn(gz - (float)z0);
        i0[j] = z0 * 48 + ((x0 + 5 * z0) & 15);
        i1[j] = (z0 + 1) * 48 + ((x0 + 5 * (z0 + 1)) & 15);
    }

    size_t obase = ((size_t)(b * 12) << 20) + (size_t)((y << 10) + xp);

    #pragma unroll
    for (int q = 0; q < 3; ++q) {
        __half2 acc01[4], acc23[4];        // [px], (c0,c1)/(c2,c3) packed
        #pragma unroll
        for (int j = 0; j < 4; ++j) {
            uint4 A = smem[i0[j] + q * 16];   // (z0): c0..c3 @ x0, x0+1
            uint4 B = smem[i1[j] + q * 16];   // (z0+1)
            __half2 a01 = *(__half2*)&A.x, a23 = *(__half2*)&A.y;
            __half2 b01 = *(__half2*)&A.z, b23 = *(__half2*)&A.w;
            __half2 c01 = *(__half2*)&B.x, c23 = *(__half2*)&B.y;
            __half2 d01 = *(__half2*)&B.z, d23 = *(__half2*)&B.w;
            __half2 e01 = __hfma2(fx2[j], __hsub2(b01, a01), a01);
            __half2 e23 = __hfma2(fx2[j], __hsub2(b23, a23), a23);
            __half2 f01 = __hfma2(fx2[j], __hsub2(d01, c01), c01);
            __half2 f23 = __hfma2(fx2[j], __hsub2(d23, c23), c23);
            acc01[j] = __hfma2(fz2[j], __hsub2(f01, e01), e01);
            acc23[j] = __hfma2(fz2[j], __hsub2(f23, e23), e23);
        }
        f4 v;
        v = (f4){__low2float(acc01[0]),  __low2float(acc01[1]),
                 __low2float(acc01[2]),  __low2float(acc01[3])};
        *reinterpret_cast<f4*>(out + obase + ((size_t)(4*q+0) << 20)) = v;
        v = (f4){__high2float(acc01[0]), __high2float(acc01[1]),
                 __high2float(acc01[2]), __high2float(acc01[3])};
        *reinterpret_cast<f4*>(out + obase + ((size_t)(4*q+1) << 20)) = v;
        v = (f4){__low2float(acc23[0]),  __low2float(acc23[1]),
                 __low2float(acc23[2]),  __low2float(acc23[3])};
        *reinterpret_cast<f4*>(out + obase + ((size_t)(4*q+2) << 20)) = v;
        v = (f4){__high2float(acc23[0]), __high2float(acc23[1]),
                 __high2float(acc23[2]), __high2float(acc23[3])};
        *reinterpret_cast<f4*>(out + obase + ((size_t)(4*q+3) << 20)) = v;
    }
}

extern "C" void kernel_launch(void* const* d_in, const int* in_sizes, int n_in,
                              void* d_out, int out_size, void* d_ws, size_t ws_size,
                              hipStream_t stream) {
    const float* grid  = (const float*)d_in[0];
    const float* guide = (const float*)d_in[1];
    float* out = (float*)d_out;

    // 4 batches * 1024 rows = 4096 blocks; 256 threads = 4 px/thread.
    dim3 grd(4096), blk(256);
    hipLaunchKernelGGL(bilateral_slice_kernel, grd, blk, 0, stream,
                       grid, guide, out);
}